// Round 8
// baseline (450.878 us; speedup 1.0000x reference)
//
#include <hip/hip_runtime.h>

#define NB 4
#define NS 1024
#define NH 256
#define NR 65536
#define NF 768
#define NK 512

typedef __attribute__((ext_vector_type(8))) short bf16x8;
typedef __attribute__((ext_vector_type(16))) float f32x16;

static __device__ __forceinline__ unsigned short f2bf(float f) {
  unsigned int u = __builtin_bit_cast(unsigned int, f);
  u += 0x7FFFu + ((u >> 16) & 1u);   // RTNE
  return (unsigned short)(u >> 16);
}

// HW packed convert: lo = bf16(a), hi = bf16(b), RTNE.
static __device__ __forceinline__ unsigned cvt_pk(float a, float b) {
  unsigned r;
  asm("v_cvt_pk_bf16_f32 %0, %1, %2" : "=v"(r) : "v"(a), "v"(b));
  return r;
}

// Raw barrier: lgkmcnt(0) only -- does NOT drain vmcnt, so in-flight global
// loads survive the barrier.
#define BARRIER()                                            \
  do {                                                       \
    asm volatile("s_waitcnt lgkmcnt(0)" ::: "memory");       \
    __builtin_amdgcn_s_barrier();                            \
    asm volatile("" ::: "memory");                           \
  } while (0)

// Combined prep for 32x32x16 fragments (same layouts as R7):
// blocks [0,192) pack W1, [192,288) pack W2, block 288 detects id width.
__global__ void prep_all(const float* __restrict__ w1, const float* __restrict__ w2,
                         const int* __restrict__ ids,
                         unsigned short* __restrict__ w1f,
                         unsigned short* __restrict__ w2f,
                         int* __restrict__ flag) {
  int bid = blockIdx.x;
  if (bid < 192) {
    // W1F unit u = ((c*4 + wn)*32 + s)*64 + lane holds
    // W1[k = s*16 + (lane>>5)*8 + j][n1 = c*128 + wn*32 + (lane&31)], j=0..7
    int t = bid * 256 + threadIdx.x;          // 49152 units
    int l = t & 63;
    int s = (t >> 6) & 31;
    int wn = (t >> 11) & 3;
    int c = t >> 13;
    int n1 = c * 128 + wn * 32 + (l & 31);
    int k0 = s * 16 + (l >> 5) * 8;
    uint4 pk;
    unsigned short v[8];
#pragma unroll
    for (int j = 0; j < 8; ++j) v[j] = f2bf(w1[(size_t)(k0 + j) * NF + n1]);
    pk.x = v[0] | ((unsigned)v[1] << 16);
    pk.y = v[2] | ((unsigned)v[3] << 16);
    pk.z = v[4] | ((unsigned)v[5] << 16);
    pk.w = v[6] | ((unsigned)v[7] << 16);
    *(uint4*)(w1f + (size_t)t * 8) = pk;
  } else if (bid < 288) {
    // W2F unit u = (((wn*2 + nt)*6 + c)*8 + ks)*64 + lane holds
    // W2[k2 = c*128 + ks*16 + (lane>>5)*8 + j][n2 = wn*64 + nt*32 + (lane&31)]
    int t = (bid - 192) * 256 + threadIdx.x;  // 24576 units
    int l = t & 63;
    int ks = (t >> 6) & 7;
    int rest = t >> 9;                        // (wn*2+nt)*6 + c
    int c = rest % 6;
    int wnt = rest / 6;                       // wn*2 + nt
    int nt = wnt & 1;
    int wn = wnt >> 1;
    int n2 = wn * 64 + nt * 32 + (l & 31);
    int k2 = c * 128 + ks * 16 + (l >> 5) * 8;
    uint4 pk;
    unsigned short v[8];
#pragma unroll
    for (int j = 0; j < 8; ++j) v[j] = f2bf(w2[(size_t)(k2 + j) * NH + n2]);
    pk.x = v[0] | ((unsigned)v[1] << 16);
    pk.y = v[2] | ((unsigned)v[3] << 16);
    pk.z = v[4] | ((unsigned)v[5] << 16);
    pk.w = v[6] | ((unsigned)v[7] << 16);
    *(uint4*)(w2f + (size_t)t * 8) = pk;
  } else {
    __shared__ int anynz;
    if (threadIdx.x == 0) anynz = 0;
    __syncthreads();
    int acc = 0;
    for (int i = threadIdx.x; i < 8192; i += 256) acc |= ids[2 * i + 1];
    if (acc != 0) atomicOr(&anynz, 1);
    __syncthreads();
    if (threadIdx.x == 0) flag[0] = (anynz == 0) ? 1 : 0;  // 1 => int64
  }
}

// Fused: gather -> GEMM1(relu,+b1) -> GEMM2(+b2).
// 64 rows/block, 8 waves (512 thr) in 2M x 4N grid; VGPR <= 128 targeted so
// 2 blocks/CU = 16 waves/CU = 4 waves/SIMD (2x the latency hiding of the
// 4-wave variant). Weight loads fragment-packed (R4); 32x32x16 MFMA (R7);
// wave wm owns rows wm*32..+32, wave wn owns n-slice wn*32 (GEMM1) / wn*64
// (GEMM2). C/D: col=lane&31, row=(reg&3)+8*(reg>>2)+4*(lane>>5).
__global__ __launch_bounds__(512, 4)
void fused_relffn(const float* __restrict__ span, const int* __restrict__ ids,
                  const float* __restrict__ b1, const float* __restrict__ b2,
                  const unsigned short* __restrict__ w1f,
                  const unsigned short* __restrict__ w2f,
                  const int* __restrict__ flagp, float* __restrict__ out) {
  __shared__ __align__(16) unsigned short As[64 * 512];  // 64 KB, swizzled
  __shared__ __align__(16) unsigned short Hs[64 * 128];  // 16 KB, swizzled

  const int tid = threadIdx.x;
  const int blk = blockIdx.x;
  const int bb = blk >> 10;              // batch
  const int r0 = (blk & 1023) << 6;      // first relation row
  const int lane = tid & 63;
  const int w = tid >> 6;                // wave 0..7
  const int wm = w >> 2;                 // row-tile 0..1 (32 rows)
  const int wn = w & 3;                  // col-slice 0..3
  const int l31 = lane & 31;
  const int l5 = lane >> 5;              // 0..1
  const int is64 = flagp[0];

  // Packed W1 base for slice wn: + c*65536 per chunk, + s*512 per k-step.
  const unsigned short* w1base = w1f + wn * 16384 + lane * 8;
  // Packed W2 base for slice wn: + nt*24576 + c*4096 + ks*512.
  const unsigned short* w2base = w2f + wn * 49152 + lane * 8;

  // chunk-0 wf prologue: in flight across the gather + barrier.
  bf16x8 wf[2];
  wf[0] = *(const bf16x8*)(w1base);
  wf[1] = *(const bf16x8*)(w1base + 512);

  // ---- gather A tile: 64 rows x 512, f32 -> bf16, swizzled ----
  {
    const long pair0 = ((long)bb * NR + r0) * 2;
    int idv[8];
#pragma unroll
    for (int j = 0; j < 8; ++j) {
      int g = tid + j * 512;
      int row = g >> 6;
      int kc = g & 63;
      long pidx = pair0 + row * 2 + (kc >> 5);
      idv[j] = is64 ? ids[pidx * 2] : ids[pidx];
    }
#pragma unroll
    for (int j = 0; j < 8; ++j) {
      int g = tid + j * 512;
      int row = g >> 6;
      int kc = g & 63;
      const float* src = span + ((size_t)bb * NS + idv[j]) * NH + (kc & 31) * 8;
      float4 v0 = *(const float4*)src;
      float4 v1 = *(const float4*)(src + 4);
      uint4 pk;
      pk.x = cvt_pk(v0.x, v0.y);
      pk.y = cvt_pk(v0.z, v0.w);
      pk.z = cvt_pk(v1.x, v1.y);
      pk.w = cvt_pk(v1.z, v1.w);
      int idx = row * 512 + ((kc * 8) ^ ((row & 7) << 3));  // XOR swizzle
      *(uint4*)&As[idx] = pk;
    }
  }
  BARRIER();

  // Per-lane row for both MFMA B-operands and the output: arow.
  const int arow = wm * 32 + l31;
  const int swz = (arow & 7) << 3;
  const unsigned short* asrow = &As[arow * 512];
  const unsigned short* hsrow = &Hs[arow * 128];
  unsigned short* hsroww = &Hs[arow * 128];

  f32x16 acc2[2];   // [nt]
#pragma unroll
  for (int nt = 0; nt < 2; ++nt)
#pragma unroll
    for (int r = 0; r < 16; ++r) acc2[nt][r] = 0.f;

  for (int c = 0; c < 6; ++c) {
    const unsigned short* wp = w1base + c * 65536;
    // ---- GEMM1 sweep: 32 k-steps, af double-buffered, wf rolling 2-deep ----
    f32x16 acc1;
#pragma unroll
    for (int r = 0; r < 16; ++r) acc1[r] = 0.f;

    bf16x8 afp[2];
    afp[0] = *(const bf16x8*)&asrow[(l5 * 8) ^ swz];
#pragma unroll
    for (int s = 0; s < 32; ++s) {
      const int cur = s & 1;
      if (s < 31) {
        int col = (s + 1) * 16 + l5 * 8;
        afp[cur ^ 1] = *(const bf16x8*)&asrow[col ^ swz];
      }
      bf16x8 cw = wf[cur];
      if (s < 30) wf[cur] = *(const bf16x8*)(wp + (s + 2) * 512);
      __builtin_amdgcn_s_setprio(1);
      acc1 = __builtin_amdgcn_mfma_f32_32x32x16_bf16(cw, afp[cur], acc1, 0, 0, 0);
      __builtin_amdgcn_s_setprio(0);
    }

    // Prefetch (all survive the lgkm-only barriers): this chunk's vf
    // prologue + next chunk's wf prologue.
    const unsigned short* w2p = w2base + c * 4096;
    bf16x8 vf[2][2];   // [depth][nt]
    vf[0][0] = *(const bf16x8*)(w2p);
    vf[0][1] = *(const bf16x8*)(w2p + 24576);
    vf[1][0] = *(const bf16x8*)(w2p + 512);
    vf[1][1] = *(const bf16x8*)(w2p + 24576 + 512);
    if (c < 5) {
      const unsigned short* np = w1base + (c + 1) * 65536;
      wf[0] = *(const bf16x8*)(np);
      wf[1] = *(const bf16x8*)(np + 512);
    }

    BARRIER();   // prior GEMM2's Hs reads done before overwrite
    // ---- pack: bias + relu -> bf16 into Hs (rows arow, cols wn*32..+32) ----
#pragma unroll
    for (int g = 0; g < 4; ++g) {
      int nl = wn * 32 + g * 8 + 4 * l5;
      float4 bv = *(const float4*)(b1 + c * 128 + nl);
      float x0 = fmaxf(acc1[4 * g + 0] + bv.x, 0.0f);
      float x1 = fmaxf(acc1[4 * g + 1] + bv.y, 0.0f);
      float x2 = fmaxf(acc1[4 * g + 2] + bv.z, 0.0f);
      float x3 = fmaxf(acc1[4 * g + 3] + bv.w, 0.0f);
      uint2 pk;
      pk.x = cvt_pk(x0, x1);
      pk.y = cvt_pk(x2, x3);
      *(uint2*)&hsroww[nl ^ swz] = pk;
    }
    BARRIER();
    // ---- GEMM2: 8 k-steps, hf double-buffered, vf rolling 2-deep ----
    bf16x8 hfp[2];
    hfp[0] = *(const bf16x8*)&hsrow[(l5 * 8) ^ swz];
#pragma unroll
    for (int ks = 0; ks < 8; ++ks) {
      const int cur = ks & 1;
      if (ks < 7) {
        int col = (ks + 1) * 16 + l5 * 8;
        hfp[cur ^ 1] = *(const bf16x8*)&hsrow[col ^ swz];
      }
      bf16x8 v0 = vf[cur][0], v1 = vf[cur][1];
      if (ks < 6) {
        vf[cur][0] = *(const bf16x8*)(w2p + (ks + 2) * 512);
        vf[cur][1] = *(const bf16x8*)(w2p + 24576 + (ks + 2) * 512);
      }
      __builtin_amdgcn_s_setprio(1);
      acc2[0] = __builtin_amdgcn_mfma_f32_32x32x16_bf16(v0, hfp[cur], acc2[0], 0, 0, 0);
      acc2[1] = __builtin_amdgcn_mfma_f32_32x32x16_bf16(v1, hfp[cur], acc2[1], 0, 0, 0);
      __builtin_amdgcn_s_setprio(0);
    }
  }

  // ---- epilogue: +b2, float4 stores ----
  float* orow = out + ((size_t)bb * NR + r0 + arow) * NH;
#pragma unroll
  for (int nt = 0; nt < 2; ++nt) {
#pragma unroll
    for (int g = 0; g < 4; ++g) {
      int n0 = wn * 64 + nt * 32 + g * 8 + 4 * l5;
      float4 bv = *(const float4*)(b2 + n0);
      float4 o;
      o.x = acc2[nt][4 * g + 0] + bv.x;
      o.y = acc2[nt][4 * g + 1] + bv.y;
      o.z = acc2[nt][4 * g + 2] + bv.z;
      o.w = acc2[nt][4 * g + 3] + bv.w;
      *(float4*)(orow + n0) = o;
    }
  }
}

extern "C" void kernel_launch(void* const* d_in, const int* in_sizes, int n_in,
                              void* d_out, int out_size, void* d_ws, size_t ws_size,
                              hipStream_t stream) {
  const float* span = (const float*)d_in[0];
  const int* ids = (const int*)d_in[1];
  const float* W1 = (const float*)d_in[2];
  const float* b1 = (const float*)d_in[3];
  const float* W2 = (const float*)d_in[4];
  const float* b2 = (const float*)d_in[5];
  float* out = (float*)d_out;

  char* ws = (char*)d_ws;
  int* flag = (int*)ws;
  unsigned short* w1f = (unsigned short*)(ws + 64);                    // 49152*16B
  unsigned short* w2f = (unsigned short*)(ws + 64 + NF * NK * 2);      // 24576*16B

  prep_all<<<289, 256, 0, stream>>>(W1, W2, ids, w1f, w2f, flag);
  fused_relffn<<<4096, 512, 0, stream>>>(span, ids, b1, b2, w1f, w2f, flag, out);
}

// Round 9
// 363.796 us; speedup vs baseline: 1.2394x; 1.2394x over previous
//
#include <hip/hip_runtime.h>

#define NB 4
#define NS 1024
#define NH 256
#define NR 65536
#define NF 768
#define NK 512

typedef __attribute__((ext_vector_type(8))) short bf16x8;
typedef __attribute__((ext_vector_type(4))) float f32x4;

static __device__ __forceinline__ unsigned short f2bf(float f) {
  unsigned int u = __builtin_bit_cast(unsigned int, f);
  u += 0x7FFFu + ((u >> 16) & 1u);   // RTNE
  return (unsigned short)(u >> 16);
}

// HW packed convert: lo = bf16(a), hi = bf16(b), RTNE.
static __device__ __forceinline__ unsigned cvt_pk(float a, float b) {
  unsigned r;
  asm("v_cvt_pk_bf16_f32 %0, %1, %2" : "=v"(r) : "v"(a), "v"(b));
  return r;
}

// Raw barrier: lgkmcnt(0) only -- in-flight global loads survive it.
#define BARRIER()                                            \
  do {                                                       \
    asm volatile("s_waitcnt lgkmcnt(0)" ::: "memory");       \
    __builtin_amdgcn_s_barrier();                            \
    asm volatile("" ::: "memory");                           \
  } while (0)

// Combined prep (R5 16x16 fragment layouts): blocks [0,192) pack W1,
// [192,288) pack W2, block 288 detects rel_ids element width.
__global__ void prep_all(const float* __restrict__ w1, const float* __restrict__ w2,
                         const int* __restrict__ ids,
                         unsigned short* __restrict__ w1f,
                         unsigned short* __restrict__ w2f,
                         int* __restrict__ flag) {
  int bid = blockIdx.x;
  if (bid < 192) {
    // W1F unit u = (((c*4 + w)*2 + half)*16 + kk)*64 + lane holds
    // W1col[row = c*128+w*32+half*16+(lane&15)][k = kk*32+(lane>>4)*8 +0..7]
    int t = bid * 256 + threadIdx.x;
    int l = t & 63;
    int kk = (t >> 6) & 15;
    int half = (t >> 10) & 1;
    int w = (t >> 11) & 3;
    int c = t >> 13;
    int row = c * 128 + w * 32 + half * 16 + (l & 15);
    int k0 = kk * 32 + (l >> 4) * 8;
    uint4 pk;
    unsigned short v[8];
#pragma unroll
    for (int j = 0; j < 8; ++j) v[j] = f2bf(w1[(size_t)(k0 + j) * NF + row]);
    pk.x = v[0] | ((unsigned)v[1] << 16);
    pk.y = v[2] | ((unsigned)v[3] << 16);
    pk.z = v[4] | ((unsigned)v[5] << 16);
    pk.w = v[6] | ((unsigned)v[7] << 16);
    *(uint4*)(w1f + (size_t)t * 8) = pk;
  } else if (bid < 288) {
    // W2F unit u = (((w*4 + nj)*6 + c)*4 + kq)*64 + lane holds
    // W2col[row = w*64+nj*16+(lane&15)][k = c*128+kq*32+(lane>>4)*8 +0..7]
    int t = (bid - 192) * 256 + threadIdx.x;
    int l = t & 63;
    int kq = (t >> 6) & 3;
    int rest = t >> 8;
    int c = rest % 6;
    int wn = rest / 6;
    int nj = wn & 3;
    int w = wn >> 2;
    int row = w * 64 + nj * 16 + (l & 15);
    int k = c * 128 + kq * 32 + (l >> 4) * 8;
    uint4 pk;
    unsigned short v[8];
#pragma unroll
    for (int j = 0; j < 8; ++j) v[j] = f2bf(w2[(size_t)(k + j) * NH + row]);
    pk.x = v[0] | ((unsigned)v[1] << 16);
    pk.y = v[2] | ((unsigned)v[3] << 16);
    pk.z = v[4] | ((unsigned)v[5] << 16);
    pk.w = v[6] | ((unsigned)v[7] << 16);
    *(uint4*)(w2f + (size_t)t * 8) = pk;
  } else {
    __shared__ int anynz;
    if (threadIdx.x == 0) anynz = 0;
    __syncthreads();
    int acc = 0;
    for (int i = threadIdx.x; i < 8192; i += 256) acc |= ids[2 * i + 1];
    if (acc != 0) atomicOr(&anynz, 1);
    __syncthreads();
    if (threadIdx.x == 0) flag[0] = (anynz == 0) ? 1 : 0;  // 1 => int64
  }
}

// Fused: gather -> 6x{ [GEMM1(c) || GEMM2(c-1) interleaved] bar pack(c) bar }
// -> GEMM2(5) -> epilogue. 64 rows/block, 4 waves, N-split.
// Un-paired GEMM1 frees 32 acc regs -> deeper af/wf pipelines; the 4 G2
// MFMAs per kk are independent of af/wf and fill residual stall slots.
__global__ __launch_bounds__(256, 2)
void fused_relffn(const float* __restrict__ span, const int* __restrict__ ids,
                  const float* __restrict__ b1, const float* __restrict__ b2,
                  const unsigned short* __restrict__ w1f,
                  const unsigned short* __restrict__ w2f,
                  const int* __restrict__ flagp, float* __restrict__ out) {
  __shared__ __align__(16) unsigned short As[64 * 512];  // 64 KB, swizzled
  __shared__ __align__(16) unsigned short Hs[64 * 128];  // 16 KB, swizzled

  const int tid = threadIdx.x;
  // XCD-aware swizzle (4096 = 8*512, bijective): contiguous 512-block chunks
  // per XCD -> weights (1.18 MB) + 1 span batch (1 MB) fit the 4 MB L2.
  const int blk0 = blockIdx.x;
  const int blk = (blk0 & 7) * 512 + (blk0 >> 3);
  const int bb = blk >> 10;              // batch
  const int r0 = (blk & 1023) << 6;      // first relation row
  const int lane = tid & 63;
  const int w = tid >> 6;                // wave 0..3
  const int l15 = lane & 15;
  const int lq = lane >> 4;              // 0..3
  const int is64 = flagp[0];

  // Packed W1 base: + c*65536 per chunk; half1 at +8192; + kk*512.
  const unsigned short* w1base = w1f + w * 16384 + lane * 8;
  // Packed W2 base: + nj*12288 + c*2048 + kq*512.
  const unsigned short* w2base = w2f + w * 49152 + lane * 8;

  // wfc rolling buffer (depth 4, 3-ahead): chunk-0 prologue slots 0..2
  // issued BEFORE the gather so L2 latency hides under it.
  bf16x8 wfc[4][2];
#pragma unroll
  for (int s = 0; s < 3; ++s) {
    wfc[s][0] = *(const bf16x8*)(w1base + s * 512);
    wfc[s][1] = *(const bf16x8*)(w1base + 8192 + s * 512);
  }

  // ---- gather A tile: ids preloaded, then unrolled load/convert ----
  {
    const long pair0 = ((long)bb * NR + r0) * 2;
    int idv[16];
#pragma unroll
    for (int j = 0; j < 16; ++j) {
      int g = tid + j * 256;
      int row = g >> 6;
      int kc = g & 63;
      long pidx = pair0 + row * 2 + (kc >> 5);
      idv[j] = is64 ? ids[pidx * 2] : ids[pidx];
    }
#pragma unroll
    for (int j = 0; j < 16; ++j) {
      int g = tid + j * 256;
      int row = g >> 6;
      int kc = g & 63;
      const float* src = span + ((size_t)bb * NS + idv[j]) * NH + (kc & 31) * 8;
      float4 v0 = *(const float4*)src;
      float4 v1 = *(const float4*)(src + 4);
      uint4 pk;
      pk.x = cvt_pk(v0.x, v0.y);
      pk.y = cvt_pk(v0.z, v0.w);
      pk.z = cvt_pk(v1.x, v1.y);
      pk.w = cvt_pk(v1.z, v1.w);
      int idx = row * 512 + ((kc * 8) ^ ((row & 7) << 3));  // XOR swizzle
      *(uint4*)&As[idx] = pk;
    }
  }
  BARRIER();

  f32x4 acc2[4][4];
#pragma unroll
  for (int mi = 0; mi < 4; ++mi)
#pragma unroll
    for (int nj = 0; nj < 4; ++nj) {
      f32x4 z = {0.f, 0.f, 0.f, 0.f};
      acc2[mi][nj] = z;
    }

  bf16x8 afp[3][4];   // af rolling, depth 3 (2-ahead: 116-cy coverage)
  bf16x8 hfq[3];      // hf rolling, depth 3
  bf16x8 vfp[2][4];   // vf rolling by kq parity

  for (int c = 0; c < 6; ++c) {
    const unsigned short* wp = w1base + c * 65536;
    const unsigned short* w2prev = w2base + (c - 1) * 2048;  // G2 chunk c-1

    f32x4 acc1[4][2];
#pragma unroll
    for (int mi = 0; mi < 4; ++mi)
#pragma unroll
      for (int ni = 0; ni < 2; ++ni) {
        f32x4 z = {0.f, 0.f, 0.f, 0.f};
        acc1[mi][ni] = z;
      }

    // body prologue: afp slots 0,1 (kk=0,1); hfq slots 0,1 (kk=0,1; Hs(c-1))
#pragma unroll
    for (int s = 0; s < 2; ++s)
#pragma unroll
      for (int mi = 0; mi < 4; ++mi) {
        int row = mi * 16 + l15;
        int kidx = s * 32 + lq * 8;
        afp[s][mi] = *(const bf16x8*)&As[row * 512 + (kidx ^ ((row & 7) << 3))];
      }
    if (c > 0) {
#pragma unroll
      for (int s = 0; s < 2; ++s) {
        int row = (s & 3) * 16 + l15;                 // mi2 = s&3, kq = 0
        int kidx = lq * 8;
        hfq[s] = *(const bf16x8*)&Hs[row * 128 + (kidx ^ ((row & 7) << 3))];
      }
    }

#pragma unroll
    for (int kk = 0; kk < 16; ++kk) {
      // afp prefetch: kk+2 into slot (kk+2)%3
      if (kk < 14) {
#pragma unroll
        for (int mi = 0; mi < 4; ++mi) {
          int row = mi * 16 + l15;
          int kidx = (kk + 2) * 32 + lq * 8;
          afp[(kk + 2) % 3][mi] = *(const bf16x8*)&As[row * 512 + (kidx ^ ((row & 7) << 3))];
        }
      }
      // hfq prefetch: kk+2 -> (kq2=(kk+2)>>2, mi2=(kk+2)&3)
      if (c > 0 && kk < 14) {
        int row = ((kk + 2) & 3) * 16 + l15;
        int kidx = ((kk + 2) >> 2) * 32 + lq * 8;
        hfq[(kk + 2) % 3] = *(const bf16x8*)&Hs[row * 128 + (kidx ^ ((row & 7) << 3))];
      }
      // wfc prefetch: kk+3 into slot (kk+3)&3
      if (kk < 13) {
        wfc[(kk + 3) & 3][0] = *(const bf16x8*)(wp + (kk + 3) * 512);
        wfc[(kk + 3) & 3][1] = *(const bf16x8*)(wp + 8192 + (kk + 3) * 512);
      }
      // vfp prefetch: one fragment of kq+1 per kk (kk 0..11)
      if (c > 0 && kk < 12) {
        int kq1 = (kk >> 2) + 1;
        vfp[kq1 & 1][kk & 3] = *(const bf16x8*)(w2prev + (kk & 3) * 12288 + kq1 * 512);
      }

      __builtin_amdgcn_s_setprio(1);
      // 8 G1 MFMAs
#pragma unroll
      for (int mi = 0; mi < 4; ++mi) {
        bf16x8 a = afp[kk % 3][mi];
        acc1[mi][0] = __builtin_amdgcn_mfma_f32_16x16x32_bf16(wfc[kk & 3][0], a, acc1[mi][0], 0, 0, 0);
        acc1[mi][1] = __builtin_amdgcn_mfma_f32_16x16x32_bf16(wfc[kk & 3][1], a, acc1[mi][1], 0, 0, 0);
      }
      // 4 G2 MFMAs (chunk c-1), independent of af/wf
      if (c > 0) {
        const int mi2 = kk & 3;
        const int kq = kk >> 2;
        bf16x8 h = hfq[kk % 3];
#pragma unroll
        for (int nj = 0; nj < 4; ++nj)
          acc2[mi2][nj] = __builtin_amdgcn_mfma_f32_16x16x32_bf16(vfp[kq & 1][nj], h, acc2[mi2][nj], 0, 0, 0);
      }
      __builtin_amdgcn_s_setprio(0);
    }

    // issue next-body streams; they stay in flight across the barriers:
    // wfc(c+1) slots 0..2 and vfp[0] of W2(c) (used by next body's G2 / G2(5)).
    if (c < 5) {
      const unsigned short* np = w1base + (c + 1) * 65536;
#pragma unroll
      for (int s = 0; s < 3; ++s) {
        wfc[s][0] = *(const bf16x8*)(np + s * 512);
        wfc[s][1] = *(const bf16x8*)(np + 8192 + s * 512);
      }
    }
    {
      const unsigned short* w2cur = w2base + c * 2048;
#pragma unroll
      for (int nj = 0; nj < 4; ++nj)
        vfp[0][nj] = *(const bf16x8*)(w2cur + nj * 12288);
    }

    BARRIER();   // G2(c-1) Hs reads done before overwrite
    // ---- pack(c): bias + relu -> bf16 into Hs ----
#pragma unroll
    for (int ni = 0; ni < 2; ++ni) {
      int n0 = c * 128 + w * 32 + ni * 16 + lq * 4;
      float4 bv = *(const float4*)(b1 + n0);
#pragma unroll
      for (int mi = 0; mi < 4; ++mi) {
        f32x4 a = acc1[mi][ni];
        float x0 = fmaxf(a[0] + bv.x, 0.0f);
        float x1 = fmaxf(a[1] + bv.y, 0.0f);
        float x2 = fmaxf(a[2] + bv.z, 0.0f);
        float x3 = fmaxf(a[3] + bv.w, 0.0f);
        int m = mi * 16 + l15;
        int nl0 = w * 32 + ni * 16 + lq * 4;
        uint2 pk;
        pk.x = cvt_pk(x0, x1);
        pk.y = cvt_pk(x2, x3);
        *(uint2*)&Hs[m * 128 + (nl0 ^ ((m & 7) << 3))] = pk;
      }
    }
    BARRIER();
  }

  // ---- standalone GEMM2(5): same rolling structure, no G1 ----
  {
    const unsigned short* w2p = w2base + 5 * 2048;
#pragma unroll
    for (int s = 0; s < 2; ++s) {
      int row = (s & 3) * 16 + l15;
      int kidx = lq * 8;
      hfq[s] = *(const bf16x8*)&Hs[row * 128 + (kidx ^ ((row & 7) << 3))];
    }
#pragma unroll
    for (int kk = 0; kk < 16; ++kk) {
      if (kk < 14) {
        int row = ((kk + 2) & 3) * 16 + l15;
        int kidx = ((kk + 2) >> 2) * 32 + lq * 8;
        hfq[(kk + 2) % 3] = *(const bf16x8*)&Hs[row * 128 + (kidx ^ ((row & 7) << 3))];
      }
      if (kk < 12) {
        int kq1 = (kk >> 2) + 1;
        vfp[kq1 & 1][kk & 3] = *(const bf16x8*)(w2p + (kk & 3) * 12288 + kq1 * 512);
      }
      const int mi2 = kk & 3;
      const int kq = kk >> 2;
      bf16x8 h = hfq[kk % 3];
      __builtin_amdgcn_s_setprio(1);
#pragma unroll
      for (int nj = 0; nj < 4; ++nj)
        acc2[mi2][nj] = __builtin_amdgcn_mfma_f32_16x16x32_bf16(vfp[kq & 1][nj], h, acc2[mi2][nj], 0, 0, 0);
      __builtin_amdgcn_s_setprio(0);
    }
  }

  // ---- epilogue: +b2, float4 stores ----
#pragma unroll
  for (int nj = 0; nj < 4; ++nj) {
    int n0 = w * 64 + nj * 16 + lq * 4;
    float4 bv = *(const float4*)(b2 + n0);
#pragma unroll
    for (int mi = 0; mi < 4; ++mi) {
      int m = mi * 16 + l15;
      f32x4 a = acc2[mi][nj];
      float4 o;
      o.x = a[0] + bv.x; o.y = a[1] + bv.y; o.z = a[2] + bv.z; o.w = a[3] + bv.w;
      *(float4*)(out + ((size_t)bb * NR + r0 + m) * NH + n0) = o;
    }
  }
}

extern "C" void kernel_launch(void* const* d_in, const int* in_sizes, int n_in,
                              void* d_out, int out_size, void* d_ws, size_t ws_size,
                              hipStream_t stream) {
  const float* span = (const float*)d_in[0];
  const int* ids = (const int*)d_in[1];
  const float* W1 = (const float*)d_in[2];
  const float* b1 = (const float*)d_in[3];
  const float* W2 = (const float*)d_in[4];
  const float* b2 = (const float*)d_in[5];
  float* out = (float*)d_out;

  char* ws = (char*)d_ws;
  int* flag = (int*)ws;
  unsigned short* w1f = (unsigned short*)(ws + 64);                    // 49152*16B
  unsigned short* w2f = (unsigned short*)(ws + 64 + NF * NK * 2);      // 24576*16B

  prep_all<<<289, 256, 0, stream>>>(W1, W2, ids, w1f, w2f, flag);
  fused_relffn<<<4096, 256, 0, stream>>>(span, ids, b1, b2, w1f, w2f, flag, out);
}